// Round 2
// 487.497 us; speedup vs baseline: 1.0073x; 1.0073x over previous
//
#include <hip/hip_runtime.h>
#include <math.h>

#define B_ 2048
#define N_ 512
#define U_ 64

// clang native vector type: layout-identical to float4, accepted by
// __builtin_nontemporal_store (HIP_vector_type is a class -> rejected).
typedef float f4 __attribute__((ext_vector_type(4)));

// Per-row cosine-sim partial: dot and norm² of a float4 fragment vs key frag
#define ROW_SIM(m4, dot, nsq) do { \
    const float x0 = (m4).x + 1e-16f, x1 = (m4).y + 1e-16f, \
                x2 = (m4).z + 1e-16f, x3 = (m4).w + 1e-16f; \
    dot = x0 * k0 + x1 * k1 + x2 * k2 + x3 * k3; \
    nsq = x0 * x0 + x1 * x1 + x2 * x2 + x3 * x3; \
} while (0)

#define WR_ROW(o, m4, wn) do { \
    (o).x = (m4).x * (1.0f - (wn) * e4.x) + (wn) * a4.x; \
    (o).y = (m4).y * (1.0f - (wn) * e4.y) + (wn) * a4.y; \
    (o).z = (m4).z * (1.0f - (wn) * e4.z) + (wn) * a4.z; \
    (o).w = (m4).w * (1.0f - (wn) * e4.w) + (wn) * a4.w; \
} while (0)

#define NT_STORE4(ptr, v) do { \
    f4 _t; _t.x = (v).x; _t.y = (v).y; _t.z = (v).z; _t.w = (v).w; \
    __builtin_nontemporal_store(_t, (f4*)(ptr)); \
} while (0)

__global__ __launch_bounds__(256) void ntm_kernel(
    const float* __restrict__ memory,   // (B,N,U)
    const float* __restrict__ kk,       // (B,U)
    const float* __restrict__ beta_p,   // (1,)
    const float* __restrict__ g_p,      // (1,)
    const float* __restrict__ sv,       // (B,3)
    const float* __restrict__ gamma_p,  // (1,)
    const float* __restrict__ w_pre,    // (B,N)
    const float* __restrict__ ev,       // (B,U)
    const float* __restrict__ av,       // (B,U)
    float* __restrict__ out_w,          // (B,N)
    float* __restrict__ out_r,          // (B,U)
    float* __restrict__ out_m)          // (B,N,U)
{
    __shared__ float s_sim[N_];     // sim, later reused to hold final w
    __shared__ float s_wg[N_];
    __shared__ float s_redA[4];
    __shared__ float s_redB[4];
    __shared__ float s_rred[4 * U_];

    const int b    = blockIdx.x;
    const int tid  = threadIdx.x;
    const int wave = tid >> 6;
    const int lane = tid & 63;
    const int sub  = lane >> 4;      // 0..3 : row subgroup within the wave
    const int l16  = lane & 15;      // 0..15: position within row group
    const int col  = l16 << 2;       // float4 column

    const float beta  = beta_p[0];
    const float g     = g_p[0];
    const float gamma = gamma_p[0];
    const float s0 = sv[b * 3 + 0], s1 = sv[b * 3 + 1], s2 = sv[b * 3 + 2];

    const size_t mem_base = (size_t)b * N_ * U_;
    const int i0 = tid, i1 = tid + 256;

    // ---- early independent small loads (hide under pass 1) ----
    const float wp0 = w_pre[(size_t)b * N_ + i0];
    const float wp1 = w_pre[(size_t)b * N_ + i1];
    const float4 e4 = *(const float4*)(ev + b * U_ + col);
    const float4 a4 = *(const float4*)(av + b * U_ + col);

    // ---- key fragment + norm: barrier-free, redundant per 16-lane group ----
    const float4 k4 = *(const float4*)(kk + b * U_ + col);
    const float k0 = k4.x + 1e-16f, k1 = k4.y + 1e-16f,
                k2 = k4.z + 1e-16f, k3 = k4.w + 1e-16f;
    float ksq = k0 * k0 + k1 * k1 + k2 * k2 + k3 * k3;
    #pragma unroll
    for (int off = 8; off; off >>= 1) ksq += __shfl_xor(ksq, off);
    const float ny = fmaxf(sqrtf(ksq), 1e-8f);

    // ---- pass 1: cosine similarity, 4 rows (loads) in flight per wave ----
    const int nb = (wave << 2) + sub;                    // base row 0..15
    const float* pm = memory + mem_base + (size_t)nb * U_ + col;
    #pragma unroll 1
    for (int n0 = 0; n0 < N_; n0 += 64) {
        const float4 m0 = *(const float4*)(pm + (size_t)(n0     ) * U_);
        const float4 m1 = *(const float4*)(pm + (size_t)(n0 + 16) * U_);
        const float4 m2 = *(const float4*)(pm + (size_t)(n0 + 32) * U_);
        const float4 m3 = *(const float4*)(pm + (size_t)(n0 + 48) * U_);
        float d0, d1, d2, d3, q0, q1, q2, q3;
        ROW_SIM(m0, d0, q0);
        ROW_SIM(m1, d1, q1);
        ROW_SIM(m2, d2, q2);
        ROW_SIM(m3, d3, q3);
        #pragma unroll
        for (int off = 8; off; off >>= 1) {
            d0 += __shfl_xor(d0, off); q0 += __shfl_xor(q0, off);
            d1 += __shfl_xor(d1, off); q1 += __shfl_xor(q1, off);
            d2 += __shfl_xor(d2, off); q2 += __shfl_xor(q2, off);
            d3 += __shfl_xor(d3, off); q3 += __shfl_xor(q3, off);
        }
        if (l16 == 0) {
            s_sim[nb + n0     ] = d0 / (fmaxf(sqrtf(q0), 1e-8f) * ny);
            s_sim[nb + n0 + 16] = d1 / (fmaxf(sqrtf(q1), 1e-8f) * ny);
            s_sim[nb + n0 + 32] = d2 / (fmaxf(sqrtf(q2), 1e-8f) * ny);
            s_sim[nb + n0 + 48] = d3 / (fmaxf(sqrtf(q3), 1e-8f) * ny);
        }
    }
    __syncthreads();                                     // (1) sim ready

    // ---- softmax(beta*sim) -> gate -> shift -> sharpen -> normalize ----
    // |beta*sim| <= beta (~5): exp range safe in fp32, skip the max pass.
    const float t0 = beta * s_sim[i0];
    const float t1 = beta * s_sim[i1];
    const float e0 = __expf(t0);
    const float e1 = __expf(t1);
    float v = e0 + e1;
    #pragma unroll
    for (int off = 32; off; off >>= 1) v += __shfl_xor(v, off);
    if (lane == 0) s_redA[wave] = v;
    __syncthreads();                                     // (2) exp-sum ready
    const float einv = 1.0f / (s_redA[0] + s_redA[1] + s_redA[2] + s_redA[3]);

    const float gc = 1.0f - g;
    s_wg[i0] = g * (e0 * einv) + gc * wp0;
    s_wg[i1] = g * (e1 * einv) + gc * wp1;
    __syncthreads();                                     // (3) wg ready

    // circular 3-tap shift + sharpen
    int nm = (i0 + N_ - 1) & (N_ - 1), np = (i0 + 1) & (N_ - 1);
    const float ws0 = s0 * s_wg[nm] + s1 * s_wg[i0] + s2 * s_wg[np];
    nm = (i1 + N_ - 1) & (N_ - 1); np = (i1 + 1) & (N_ - 1);
    const float ws1 = s0 * s_wg[nm] + s1 * s_wg[i1] + s2 * s_wg[np];
    const float wsv0 = __expf(gamma * __logf(ws0));      // ws > 0 always
    const float wsv1 = __expf(gamma * __logf(ws1));
    v = wsv0 + wsv1;
    #pragma unroll
    for (int off = 32; off; off >>= 1) v += __shfl_xor(v, off);
    if (lane == 0) s_redB[wave] = v;
    __syncthreads();                                     // (4) sharpen-sum ready
    const float winv = 1.0f / (s_redB[0] + s_redB[1] + s_redB[2] + s_redB[3]);

    const float w0 = wsv0 * winv + 1e-16f;
    const float w1 = wsv1 * winv + 1e-16f;
    s_sim[i0] = w0;                                      // reuse sim buffer as w
    s_sim[i1] = w1;
    out_w[(size_t)b * N_ + i0] = w0;
    out_w[(size_t)b * N_ + i1] = w1;
    __syncthreads();                                     // (5) w ready

    // ---- pass 2: read (r) + write (new_mem), 4 loads in flight ----
    float rxA = 0.f, ryA = 0.f, rzA = 0.f, rwA = 0.f;
    float rxB = 0.f, ryB = 0.f, rzB = 0.f, rwB = 0.f;
    float* po = out_m + mem_base + (size_t)nb * U_ + col;
    #pragma unroll 1
    for (int n0 = 0; n0 < N_; n0 += 64) {
        const float4 m0 = *(const float4*)(pm + (size_t)(n0     ) * U_);
        const float4 m1 = *(const float4*)(pm + (size_t)(n0 + 16) * U_);
        const float4 m2 = *(const float4*)(pm + (size_t)(n0 + 32) * U_);
        const float4 m3 = *(const float4*)(pm + (size_t)(n0 + 48) * U_);
        const float wn0 = s_sim[nb + n0     ];
        const float wn1 = s_sim[nb + n0 + 16];
        const float wn2 = s_sim[nb + n0 + 32];
        const float wn3 = s_sim[nb + n0 + 48];
        float4 o0, o1, o2, o3;
        WR_ROW(o0, m0, wn0);
        WR_ROW(o1, m1, wn1);
        WR_ROW(o2, m2, wn2);
        WR_ROW(o3, m3, wn3);
        // write-once stream: don't allocate in L2/L3 (protect memory's residency)
        NT_STORE4(po + (size_t)(n0     ) * U_, o0);
        NT_STORE4(po + (size_t)(n0 + 16) * U_, o1);
        NT_STORE4(po + (size_t)(n0 + 32) * U_, o2);
        NT_STORE4(po + (size_t)(n0 + 48) * U_, o3);
        rxA = fmaf(wn0, m0.x, rxA); ryA = fmaf(wn0, m0.y, ryA);
        rzA = fmaf(wn0, m0.z, rzA); rwA = fmaf(wn0, m0.w, rwA);
        rxB = fmaf(wn1, m1.x, rxB); ryB = fmaf(wn1, m1.y, ryB);
        rzB = fmaf(wn1, m1.z, rzB); rwB = fmaf(wn1, m1.w, rwB);
        rxA = fmaf(wn2, m2.x, rxA); ryA = fmaf(wn2, m2.y, ryA);
        rzA = fmaf(wn2, m2.z, rzA); rwA = fmaf(wn2, m2.w, rwA);
        rxB = fmaf(wn3, m3.x, rxB); ryB = fmaf(wn3, m3.y, ryB);
        rzB = fmaf(wn3, m3.z, rzB); rwB = fmaf(wn3, m3.w, rwB);
    }
    float rx = rxA + rxB, ry = ryA + ryB, rz = rzA + rzB, rw = rwA + rwB;
    // reduce across the 4 row-subgroups of the wave (lanes l, l^16, l^32)
    rx += __shfl_xor(rx, 16); rx += __shfl_xor(rx, 32);
    ry += __shfl_xor(ry, 16); ry += __shfl_xor(ry, 32);
    rz += __shfl_xor(rz, 16); rz += __shfl_xor(rz, 32);
    rw += __shfl_xor(rw, 16); rw += __shfl_xor(rw, 32);
    if (lane < 16) {
        s_rred[wave * U_ + col + 0] = rx;
        s_rred[wave * U_ + col + 1] = ry;
        s_rred[wave * U_ + col + 2] = rz;
        s_rred[wave * U_ + col + 3] = rw;
    }
    __syncthreads();                                     // (6) r partials ready
    if (tid < U_) {
        const float rv = s_rred[tid] + s_rred[U_ + tid]
                       + s_rred[2 * U_ + tid] + s_rred[3 * U_ + tid];
        out_r[(size_t)b * U_ + tid] = rv;
    }
}

extern "C" void kernel_launch(void* const* d_in, const int* in_sizes, int n_in,
                              void* d_out, int out_size, void* d_ws, size_t ws_size,
                              hipStream_t stream) {
    const float* memory = (const float*)d_in[0];
    const float* kk     = (const float*)d_in[1];
    const float* beta   = (const float*)d_in[2];
    const float* g      = (const float*)d_in[3];
    const float* sv     = (const float*)d_in[4];
    const float* gamma  = (const float*)d_in[5];
    const float* w_pre  = (const float*)d_in[6];
    const float* ev     = (const float*)d_in[7];
    const float* av     = (const float*)d_in[8];

    float* out   = (float*)d_out;
    float* out_w = out;                                        // B*N
    float* out_r = out + (size_t)B_ * N_;                      // B*U
    float* out_m = out + (size_t)B_ * N_ + (size_t)B_ * U_;    // B*N*U

    ntm_kernel<<<B_, 256, 0, stream>>>(memory, kk, beta, g, sv, gamma,
                                       w_pre, ev, av, out_w, out_r, out_m);
}

// Round 3
// 479.952 us; speedup vs baseline: 1.0231x; 1.0157x over previous
//
#include <hip/hip_runtime.h>
#include <math.h>

#define B_ 2048
#define N_ 512
#define U_ 64

// clang native vector type: layout-identical to float4, accepted by
// __builtin_nontemporal_store (HIP_vector_type is a class -> rejected).
typedef float f4 __attribute__((ext_vector_type(4)));

// Per-row cosine-sim partial: dot and norm² of a float4 fragment vs key frag
#define ROW_SIM(m4, dot, nsq) do { \
    const float x0 = (m4).x + 1e-16f, x1 = (m4).y + 1e-16f, \
                x2 = (m4).z + 1e-16f, x3 = (m4).w + 1e-16f; \
    dot = x0 * k0 + x1 * k1 + x2 * k2 + x3 * k3; \
    nsq = x0 * x0 + x1 * x1 + x2 * x2 + x3 * x3; \
} while (0)

#define WR_ROW(o, m4, wn) do { \
    (o).x = (m4).x * (1.0f - (wn) * e4.x) + (wn) * a4.x; \
    (o).y = (m4).y * (1.0f - (wn) * e4.y) + (wn) * a4.y; \
    (o).z = (m4).z * (1.0f - (wn) * e4.z) + (wn) * a4.z; \
    (o).w = (m4).w * (1.0f - (wn) * e4.w) + (wn) * a4.w; \
} while (0)

#define NT_STORE4(ptr, v) do { \
    f4 _t; _t.x = (v).x; _t.y = (v).y; _t.z = (v).z; _t.w = (v).w; \
    __builtin_nontemporal_store(_t, (f4*)(ptr)); \
} while (0)

__global__ __launch_bounds__(256) void ntm_kernel(
    const float* __restrict__ memory,   // (B,N,U)
    const float* __restrict__ kk,       // (B,U)
    const float* __restrict__ beta_p,   // (1,)
    const float* __restrict__ g_p,      // (1,)
    const float* __restrict__ sv,       // (B,3)
    const float* __restrict__ gamma_p,  // (1,)
    const float* __restrict__ w_pre,    // (B,N)
    const float* __restrict__ ev,       // (B,U)
    const float* __restrict__ av,       // (B,U)
    float* __restrict__ out_w,          // (B,N)
    float* __restrict__ out_r,          // (B,U)
    float* __restrict__ out_m)          // (B,N,U)
{
    __shared__ float s_sim[N_];     // sim, later reused to hold final w
    __shared__ float s_wg[N_];
    __shared__ float s_redA[4];
    __shared__ float s_redB[4];
    __shared__ float s_rred[4 * U_];

    const int b    = blockIdx.x;
    const int tid  = threadIdx.x;
    const int wave = tid >> 6;
    const int lane = tid & 63;
    const int sub  = lane >> 4;      // 0..3 : row subgroup within the wave
    const int l16  = lane & 15;      // 0..15: position within row group
    const int col  = l16 << 2;       // float4 column

    const float beta  = beta_p[0];
    const float g     = g_p[0];
    const float gamma = gamma_p[0];
    const float s0 = sv[b * 3 + 0], s1 = sv[b * 3 + 1], s2 = sv[b * 3 + 2];

    const size_t mem_base = (size_t)b * N_ * U_;
    const int i0 = tid, i1 = tid + 256;

    // ---- early independent small loads (hide under pass 1) ----
    const float wp0 = w_pre[(size_t)b * N_ + i0];
    const float wp1 = w_pre[(size_t)b * N_ + i1];

    // ---- key fragment + norm: barrier-free, redundant per 16-lane group ----
    const float4 k4 = *(const float4*)(kk + b * U_ + col);
    const float k0 = k4.x + 1e-16f, k1 = k4.y + 1e-16f,
                k2 = k4.z + 1e-16f, k3 = k4.w + 1e-16f;
    float ksq = k0 * k0 + k1 * k1 + k2 * k2 + k3 * k3;
    #pragma unroll
    for (int off = 8; off; off >>= 1) ksq += __shfl_xor(ksq, off);
    const float ny = fmaxf(sqrtf(ksq), 1e-8f);

    // ---- pass 1: cosine similarity, 8 loads (128 B) in flight per wave ----
    const int nb = (wave << 2) + sub;                    // base row 0..15
    const float* pm = memory + mem_base + (size_t)nb * U_ + col;
    #pragma unroll 1
    for (int n0 = 0; n0 < N_; n0 += 128) {
        const float4 m0 = *(const float4*)(pm + (size_t)(n0      ) * U_);
        const float4 m1 = *(const float4*)(pm + (size_t)(n0 +  16) * U_);
        const float4 m2 = *(const float4*)(pm + (size_t)(n0 +  32) * U_);
        const float4 m3 = *(const float4*)(pm + (size_t)(n0 +  48) * U_);
        const float4 m4_ = *(const float4*)(pm + (size_t)(n0 +  64) * U_);
        const float4 m5 = *(const float4*)(pm + (size_t)(n0 +  80) * U_);
        const float4 m6 = *(const float4*)(pm + (size_t)(n0 +  96) * U_);
        const float4 m7 = *(const float4*)(pm + (size_t)(n0 + 112) * U_);
        float d0, d1, d2, d3, d4, d5, d6, d7;
        float q0, q1, q2, q3, q4, q5, q6, q7;
        ROW_SIM(m0, d0, q0); ROW_SIM(m1, d1, q1);
        ROW_SIM(m2, d2, q2); ROW_SIM(m3, d3, q3);
        ROW_SIM(m4_, d4, q4); ROW_SIM(m5, d5, q5);
        ROW_SIM(m6, d6, q6); ROW_SIM(m7, d7, q7);
        #pragma unroll
        for (int off = 8; off; off >>= 1) {
            d0 += __shfl_xor(d0, off); q0 += __shfl_xor(q0, off);
            d1 += __shfl_xor(d1, off); q1 += __shfl_xor(q1, off);
            d2 += __shfl_xor(d2, off); q2 += __shfl_xor(q2, off);
            d3 += __shfl_xor(d3, off); q3 += __shfl_xor(q3, off);
            d4 += __shfl_xor(d4, off); q4 += __shfl_xor(q4, off);
            d5 += __shfl_xor(d5, off); q5 += __shfl_xor(q5, off);
            d6 += __shfl_xor(d6, off); q6 += __shfl_xor(q6, off);
            d7 += __shfl_xor(d7, off); q7 += __shfl_xor(q7, off);
        }
        if (l16 == 0) {
            s_sim[nb + n0      ] = d0 / (fmaxf(sqrtf(q0), 1e-8f) * ny);
            s_sim[nb + n0 +  16] = d1 / (fmaxf(sqrtf(q1), 1e-8f) * ny);
            s_sim[nb + n0 +  32] = d2 / (fmaxf(sqrtf(q2), 1e-8f) * ny);
            s_sim[nb + n0 +  48] = d3 / (fmaxf(sqrtf(q3), 1e-8f) * ny);
            s_sim[nb + n0 +  64] = d4 / (fmaxf(sqrtf(q4), 1e-8f) * ny);
            s_sim[nb + n0 +  80] = d5 / (fmaxf(sqrtf(q5), 1e-8f) * ny);
            s_sim[nb + n0 +  96] = d6 / (fmaxf(sqrtf(q6), 1e-8f) * ny);
            s_sim[nb + n0 + 112] = d7 / (fmaxf(sqrtf(q7), 1e-8f) * ny);
        }
    }
    __syncthreads();                                     // (1) sim ready

    // ---- softmax(beta*sim) -> gate -> shift -> sharpen -> normalize ----
    // |beta*sim| <= beta (~5): exp range safe in fp32, skip the max pass.
    const float t0 = beta * s_sim[i0];
    const float t1 = beta * s_sim[i1];
    const float e0 = __expf(t0);
    const float e1 = __expf(t1);
    float v = e0 + e1;
    #pragma unroll
    for (int off = 32; off; off >>= 1) v += __shfl_xor(v, off);
    if (lane == 0) s_redA[wave] = v;
    __syncthreads();                                     // (2) exp-sum ready
    const float einv = 1.0f / (s_redA[0] + s_redA[1] + s_redA[2] + s_redA[3]);

    const float gc = 1.0f - g;
    s_wg[i0] = g * (e0 * einv) + gc * wp0;
    s_wg[i1] = g * (e1 * einv) + gc * wp1;
    __syncthreads();                                     // (3) wg ready

    // circular 3-tap shift + sharpen
    int nm = (i0 + N_ - 1) & (N_ - 1), np = (i0 + 1) & (N_ - 1);
    const float ws0 = s0 * s_wg[nm] + s1 * s_wg[i0] + s2 * s_wg[np];
    nm = (i1 + N_ - 1) & (N_ - 1); np = (i1 + 1) & (N_ - 1);
    const float ws1 = s0 * s_wg[nm] + s1 * s_wg[i1] + s2 * s_wg[np];
    const float wsv0 = __expf(gamma * __logf(ws0));      // ws > 0 always
    const float wsv1 = __expf(gamma * __logf(ws1));
    v = wsv0 + wsv1;
    #pragma unroll
    for (int off = 32; off; off >>= 1) v += __shfl_xor(v, off);
    if (lane == 0) s_redB[wave] = v;
    __syncthreads();                                     // (4) sharpen-sum ready
    const float winv = 1.0f / (s_redB[0] + s_redB[1] + s_redB[2] + s_redB[3]);

    const float w0 = wsv0 * winv + 1e-16f;
    const float w1 = wsv1 * winv + 1e-16f;
    s_sim[i0] = w0;                                      // reuse sim buffer as w
    s_sim[i1] = w1;
    out_w[(size_t)b * N_ + i0] = w0;
    out_w[(size_t)b * N_ + i1] = w1;
    __syncthreads();                                     // (5) w ready

    // ---- pass 2: read (r) + write (new_mem), 8 loads in flight ----
    const float4 e4 = *(const float4*)(ev + b * U_ + col);
    const float4 a4 = *(const float4*)(av + b * U_ + col);
    float rxA = 0.f, ryA = 0.f, rzA = 0.f, rwA = 0.f;
    float rxB = 0.f, ryB = 0.f, rzB = 0.f, rwB = 0.f;
    float* po = out_m + mem_base + (size_t)nb * U_ + col;
    #pragma unroll 1
    for (int n0 = 0; n0 < N_; n0 += 128) {
        const float4 m0 = *(const float4*)(pm + (size_t)(n0      ) * U_);
        const float4 m1 = *(const float4*)(pm + (size_t)(n0 +  16) * U_);
        const float4 m2 = *(const float4*)(pm + (size_t)(n0 +  32) * U_);
        const float4 m3 = *(const float4*)(pm + (size_t)(n0 +  48) * U_);
        const float4 m4_ = *(const float4*)(pm + (size_t)(n0 +  64) * U_);
        const float4 m5 = *(const float4*)(pm + (size_t)(n0 +  80) * U_);
        const float4 m6 = *(const float4*)(pm + (size_t)(n0 +  96) * U_);
        const float4 m7 = *(const float4*)(pm + (size_t)(n0 + 112) * U_);
        const float wn0 = s_sim[nb + n0      ];
        const float wn1 = s_sim[nb + n0 +  16];
        const float wn2 = s_sim[nb + n0 +  32];
        const float wn3 = s_sim[nb + n0 +  48];
        const float wn4 = s_sim[nb + n0 +  64];
        const float wn5 = s_sim[nb + n0 +  80];
        const float wn6 = s_sim[nb + n0 +  96];
        const float wn7 = s_sim[nb + n0 + 112];
        float4 o0, o1, o2, o3, o4, o5, o6, o7;
        WR_ROW(o0, m0, wn0); WR_ROW(o1, m1, wn1);
        WR_ROW(o2, m2, wn2); WR_ROW(o3, m3, wn3);
        WR_ROW(o4, m4_, wn4); WR_ROW(o5, m5, wn5);
        WR_ROW(o6, m6, wn6); WR_ROW(o7, m7, wn7);
        // write-once stream: don't allocate in L2/L3 (protect memory's residency)
        NT_STORE4(po + (size_t)(n0      ) * U_, o0);
        NT_STORE4(po + (size_t)(n0 +  16) * U_, o1);
        NT_STORE4(po + (size_t)(n0 +  32) * U_, o2);
        NT_STORE4(po + (size_t)(n0 +  48) * U_, o3);
        NT_STORE4(po + (size_t)(n0 +  64) * U_, o4);
        NT_STORE4(po + (size_t)(n0 +  80) * U_, o5);
        NT_STORE4(po + (size_t)(n0 +  96) * U_, o6);
        NT_STORE4(po + (size_t)(n0 + 112) * U_, o7);
        rxA = fmaf(wn0, m0.x, rxA); ryA = fmaf(wn0, m0.y, ryA);
        rzA = fmaf(wn0, m0.z, rzA); rwA = fmaf(wn0, m0.w, rwA);
        rxB = fmaf(wn1, m1.x, rxB); ryB = fmaf(wn1, m1.y, ryB);
        rzB = fmaf(wn1, m1.z, rzB); rwB = fmaf(wn1, m1.w, rwB);
        rxA = fmaf(wn2, m2.x, rxA); ryA = fmaf(wn2, m2.y, ryA);
        rzA = fmaf(wn2, m2.z, rzA); rwA = fmaf(wn2, m2.w, rwA);
        rxB = fmaf(wn3, m3.x, rxB); ryB = fmaf(wn3, m3.y, ryB);
        rzB = fmaf(wn3, m3.z, rzB); rwB = fmaf(wn3, m3.w, rwB);
        rxA = fmaf(wn4, m4_.x, rxA); ryA = fmaf(wn4, m4_.y, ryA);
        rzA = fmaf(wn4, m4_.z, rzA); rwA = fmaf(wn4, m4_.w, rwA);
        rxB = fmaf(wn5, m5.x, rxB); ryB = fmaf(wn5, m5.y, ryB);
        rzB = fmaf(wn5, m5.z, rzB); rwB = fmaf(wn5, m5.w, rwB);
        rxA = fmaf(wn6, m6.x, rxA); ryA = fmaf(wn6, m6.y, ryA);
        rzA = fmaf(wn6, m6.z, rzA); rwA = fmaf(wn6, m6.w, rwA);
        rxB = fmaf(wn7, m7.x, rxB); ryB = fmaf(wn7, m7.y, ryB);
        rzB = fmaf(wn7, m7.z, rzB); rwB = fmaf(wn7, m7.w, rwB);
    }
    float rx = rxA + rxB, ry = ryA + ryB, rz = rzA + rzB, rw = rwA + rwB;
    // reduce across the 4 row-subgroups of the wave (lanes l, l^16, l^32)
    rx += __shfl_xor(rx, 16); rx += __shfl_xor(rx, 32);
    ry += __shfl_xor(ry, 16); ry += __shfl_xor(ry, 32);
    rz += __shfl_xor(rz, 16); rz += __shfl_xor(rz, 32);
    rw += __shfl_xor(rw, 16); rw += __shfl_xor(rw, 32);
    if (lane < 16) {
        s_rred[wave * U_ + col + 0] = rx;
        s_rred[wave * U_ + col + 1] = ry;
        s_rred[wave * U_ + col + 2] = rz;
        s_rred[wave * U_ + col + 3] = rw;
    }
    __syncthreads();                                     // (6) r partials ready
    if (tid < U_) {
        const float rv = s_rred[tid] + s_rred[U_ + tid]
                       + s_rred[2 * U_ + tid] + s_rred[3 * U_ + tid];
        out_r[(size_t)b * U_ + tid] = rv;
    }
}

extern "C" void kernel_launch(void* const* d_in, const int* in_sizes, int n_in,
                              void* d_out, int out_size, void* d_ws, size_t ws_size,
                              hipStream_t stream) {
    const float* memory = (const float*)d_in[0];
    const float* kk     = (const float*)d_in[1];
    const float* beta   = (const float*)d_in[2];
    const float* g      = (const float*)d_in[3];
    const float* sv     = (const float*)d_in[4];
    const float* gamma  = (const float*)d_in[5];
    const float* w_pre  = (const float*)d_in[6];
    const float* ev     = (const float*)d_in[7];
    const float* av     = (const float*)d_in[8];

    float* out   = (float*)d_out;
    float* out_w = out;                                        // B*N
    float* out_r = out + (size_t)B_ * N_;                      // B*U
    float* out_m = out + (size_t)B_ * N_ + (size_t)B_ * U_;    // B*N*U

    ntm_kernel<<<B_, 256, 0, stream>>>(memory, kk, beta, g, sv, gamma,
                                       w_pre, ev, av, out_w, out_r, out_m);
}

// Round 4
// 466.104 us; speedup vs baseline: 1.0535x; 1.0297x over previous
//
#include <hip/hip_runtime.h>
#include <math.h>

#define B_ 2048
#define N_ 512
#define U_ 64

// clang native vector: accepted by __builtin_nontemporal_store
typedef float f4 __attribute__((ext_vector_type(4)));

#define NT_STORE4(ptr, v) __builtin_nontemporal_store((v), (f4*)(ptr))

__global__ __launch_bounds__(512, 1) void ntm_kernel(
    const float* __restrict__ memory,   // (B,N,U)
    const float* __restrict__ kk,       // (B,U)
    const float* __restrict__ beta_p,   // (1,)
    const float* __restrict__ g_p,      // (1,)
    const float* __restrict__ sv,       // (B,3)
    const float* __restrict__ gamma_p,  // (1,)
    const float* __restrict__ w_pre,    // (B,N)
    const float* __restrict__ ev,       // (B,U)
    const float* __restrict__ av,       // (B,U)
    float* __restrict__ out_w,          // (B,N)
    float* __restrict__ out_r,          // (B,U)
    float* __restrict__ out_m)          // (B,N,U)
{
    // 128 KiB staged slice + ~5 KiB scratch -> 1 block/CU (intentional:
    // HBM request depth, not CU count, is the scarce resource here)
    __shared__ float s_mem[N_ * U_];
    __shared__ float s_sim[N_];         // sim, later reused to hold final w
    __shared__ float s_wg[N_];
    __shared__ float s_red[8];
    __shared__ float s_red2[8];
    __shared__ float s_rred[8 * U_];

    const int b    = blockIdx.x;
    const int tid  = threadIdx.x;       // 0..511
    const int wave = tid >> 6;          // 0..7
    const int lane = tid & 63;
    const int grp  = tid >> 4;          // 0..31 : 16-lane row group
    const int l16  = tid & 15;
    const int col  = l16 << 2;          // float4 column within U

    const size_t mem_base = (size_t)b * N_ * U_;

    // ---- small per-block loads FIRST (their waits then don't drain the DMA queue) ----
    const float beta  = beta_p[0];
    const float g     = g_p[0];
    const float gamma = gamma_p[0];
    const float s0 = sv[b * 3 + 0], s1 = sv[b * 3 + 1], s2 = sv[b * 3 + 2];
    const float wp = w_pre[(size_t)b * N_ + tid];
    const f4 e4 = *(const f4*)(ev + b * U_ + col);
    const f4 a4 = *(const f4*)(av + b * U_ + col);
    const f4 k4 = *(const f4*)(kk + b * U_ + col);

    // ---- async DMA: stage the whole 128 KiB memory slice into LDS ----
    // 128 chunks of 1 KiB; wave w issues chunks [16w, 16w+16).
    // Per-CU outstanding: 8 waves x 16 x 1 KiB = 128 KiB in flight.
    {
        const float* gsrc = memory + mem_base;
        #pragma unroll
        for (int i = 0; i < 16; ++i) {
            const int c = (wave << 4) + i;          // chunk id 0..127
            __builtin_amdgcn_global_load_lds(
                (const __attribute__((address_space(1))) void*)(gsrc + (c << 8) + (lane << 2)),
                (__attribute__((address_space(3))) void*)(s_mem + (c << 8)),
                16, 0, 0);
        }
    }

    // key norm while DMA is in flight (16-lane butterfly, lgkm path)
    const float k0 = k4.x + 1e-16f, k1 = k4.y + 1e-16f,
                k2 = k4.z + 1e-16f, k3 = k4.w + 1e-16f;
    float ksq = k0 * k0 + k1 * k1 + k2 * k2 + k3 * k3;
    #pragma unroll
    for (int off = 8; off; off >>= 1) ksq += __shfl_xor(ksq, off);
    const float ny = fmaxf(sqrtf(ksq), 1e-8f);

    asm volatile("s_waitcnt vmcnt(0)" ::: "memory");
    __syncthreads();                                 // (1) slice staged

    // ---- pass 1: cosine similarity from LDS ----
    #pragma unroll 4
    for (int j = 0; j < 16; ++j) {
        const int r = (j << 5) + grp;                // row 0..511
        const f4 m = *(const f4*)(s_mem + r * U_ + col);
        const float x0 = m.x + 1e-16f, x1 = m.y + 1e-16f,
                    x2 = m.z + 1e-16f, x3 = m.w + 1e-16f;
        float dot = x0 * k0 + x1 * k1 + x2 * k2 + x3 * k3;
        float nsq = x0 * x0 + x1 * x1 + x2 * x2 + x3 * x3;
        #pragma unroll
        for (int off = 8; off; off >>= 1) {
            dot += __shfl_xor(dot, off);
            nsq += __shfl_xor(nsq, off);
        }
        if (l16 == 0) s_sim[r] = dot / (fmaxf(sqrtf(nsq), 1e-8f) * ny);
    }
    __syncthreads();                                 // (2) sim ready

    // ---- softmax -> gate -> shift -> sharpen -> normalize (1 elem/thread) ----
    // |beta*sim| <= beta (~5): fp32-safe without the max pass.
    const float e0 = __expf(beta * s_sim[tid]);
    float v = e0;
    #pragma unroll
    for (int off = 32; off; off >>= 1) v += __shfl_xor(v, off);
    if (lane == 0) s_red[wave] = v;
    __syncthreads();                                 // (3) exp-sum ready
    const float einv = 1.0f / (s_red[0] + s_red[1] + s_red[2] + s_red[3]
                             + s_red[4] + s_red[5] + s_red[6] + s_red[7]);
    s_wg[tid] = g * (e0 * einv) + (1.0f - g) * wp;
    __syncthreads();                                 // (4) wg ready

    const float ws = s0 * s_wg[(tid + N_ - 1) & (N_ - 1)]
                   + s1 * s_wg[tid]
                   + s2 * s_wg[(tid + 1) & (N_ - 1)];
    const float wsv = __expf(gamma * __logf(ws));    // ws > 0 always
    v = wsv;
    #pragma unroll
    for (int off = 32; off; off >>= 1) v += __shfl_xor(v, off);
    if (lane == 0) s_red2[wave] = v;
    __syncthreads();                                 // (5) sharpen-sum ready
    const float winv = 1.0f / (s_red2[0] + s_red2[1] + s_red2[2] + s_red2[3]
                             + s_red2[4] + s_red2[5] + s_red2[6] + s_red2[7]);

    const float w0 = wsv * winv + 1e-16f;
    s_sim[tid] = w0;                                 // reuse sim buffer as w
    out_w[(size_t)b * N_ + tid] = w0;
    __syncthreads();                                 // (6) w ready

    // ---- pass 2: read r + write new_mem, all operands from LDS ----
    float rx = 0.f, ry = 0.f, rz = 0.f, rw = 0.f;
    float* po = out_m + mem_base;
    #pragma unroll 4
    for (int j = 0; j < 16; ++j) {
        const int r = (j << 5) + grp;
        const f4 m = *(const f4*)(s_mem + r * U_ + col);
        const float wn = s_sim[r];                   // broadcast LDS read
        f4 o;
        o.x = m.x * (1.0f - wn * e4.x) + wn * a4.x;
        o.y = m.y * (1.0f - wn * e4.y) + wn * a4.y;
        o.z = m.z * (1.0f - wn * e4.z) + wn * a4.z;
        o.w = m.w * (1.0f - wn * e4.w) + wn * a4.w;
        NT_STORE4(po + r * U_ + col, o);             // write-once stream
        rx = fmaf(wn, m.x, rx); ry = fmaf(wn, m.y, ry);
        rz = fmaf(wn, m.z, rz); rw = fmaf(wn, m.w, rw);
    }
    // combine the 4 groups within each wave (lanes l, l^16, l^32)
    rx += __shfl_xor(rx, 16); rx += __shfl_xor(rx, 32);
    ry += __shfl_xor(ry, 16); ry += __shfl_xor(ry, 32);
    rz += __shfl_xor(rz, 16); rz += __shfl_xor(rz, 32);
    rw += __shfl_xor(rw, 16); rw += __shfl_xor(rw, 32);
    if (lane < 16) {
        s_rred[wave * U_ + col + 0] = rx;
        s_rred[wave * U_ + col + 1] = ry;
        s_rred[wave * U_ + col + 2] = rz;
        s_rred[wave * U_ + col + 3] = rw;
    }
    __syncthreads();                                 // (7) r partials ready
    if (tid < U_) {
        float rv = 0.f;
        #pragma unroll
        for (int q = 0; q < 8; ++q) rv += s_rred[q * U_ + tid];
        out_r[(size_t)b * U_ + tid] = rv;
    }
}

extern "C" void kernel_launch(void* const* d_in, const int* in_sizes, int n_in,
                              void* d_out, int out_size, void* d_ws, size_t ws_size,
                              hipStream_t stream) {
    const float* memory = (const float*)d_in[0];
    const float* kk     = (const float*)d_in[1];
    const float* beta   = (const float*)d_in[2];
    const float* g      = (const float*)d_in[3];
    const float* sv     = (const float*)d_in[4];
    const float* gamma  = (const float*)d_in[5];
    const float* w_pre  = (const float*)d_in[6];
    const float* ev     = (const float*)d_in[7];
    const float* av     = (const float*)d_in[8];

    float* out   = (float*)d_out;
    float* out_w = out;                                        // B*N
    float* out_r = out + (size_t)B_ * N_;                      // B*U
    float* out_m = out + (size_t)B_ * N_ + (size_t)B_ * U_;    // B*N*U

    ntm_kernel<<<B_, 512, 0, stream>>>(memory, kk, beta, g, sv, gamma,
                                       w_pre, ev, av, out_w, out_r, out_m);
}